// Round 1
// baseline (185.868 us; speedup 1.0000x reference)
//
#include <hip/hip_runtime.h>
#include <math.h>

#define NB 16
#define NT 12
#define NN 2048
#define NH 16
#define NK 20

#define RPB 8     // rows per block
#define RPW 2     // rows per wave
#define CHUNK 256
#define NCH (NN / CHUNK)    // 8
#define JST (CHUNK / 64)    // 4
#define EST 20              // padded float stride per node in LDS (16B-aligned, bank-spread)
#define CCAP 64

static __device__ __forceinline__ unsigned long long shflxor64(unsigned long long v, int m) {
  unsigned lo = (unsigned)v, hi = (unsigned)(v >> 32);
  lo = (unsigned)__shfl_xor((int)lo, m, 64);
  hi = (unsigned)__shfl_xor((int)hi, m, 64);
  return ((unsigned long long)hi << 32) | lo;
}

// ---- kernel 0: state mean + 16-dim tanh embedding -------------------------
__global__ void k_emb(const float* __restrict__ x, const float* __restrict__ W,
                      const float* __restrict__ bias, float* __restrict__ emb) {
  int id = blockIdx.x * blockDim.x + threadIdx.x;
  if (id >= NB * NN) return;
  int b = id >> 11, n = id & (NN - 1);
  const float* xp = x + ((size_t)b * NT) * NN + n;
  float s = 0.0f;
#pragma unroll
  for (int t = 0; t < NT; ++t) s += xp[(size_t)t * NN];
  s = s / 12.0f;  // mean, sequential over t then divide (matches ref)
  float* e = emb + (size_t)id * NH;
#pragma unroll
  for (int h = 0; h < NH; ++h) {
    // mul-round then add-round (no contraction), tanh via double = correctly rounded f32
    float arg = __fadd_rn(__fmul_rn(s, W[h]), bias[h]);
    e[h] = (float)tanh((double)arg);
  }
}

// ---- kernel 1: A_physical row sums -> a / (sum + 1e-8) --------------------
__global__ void k_rowsum(const float* __restrict__ A, const float* __restrict__ alpha,
                         float* __restrict__ aInv) {
  int gw = (blockIdx.x * blockDim.x + threadIdx.x) >> 6;
  int lane = threadIdx.x & 63;
  if (gw >= NN) return;
  const float* row = A + (size_t)gw * NN;
  float s = 0.0f;
#pragma unroll
  for (int j = 0; j < NN / 64; ++j) s += row[lane + 64 * j];
#pragma unroll
  for (int off = 32; off; off >>= 1) s += __shfl_xor(s, off, 64);
  if (lane == 0) {
    float a = 1.0f / (1.0f + expf(-alpha[0]));
    aInv[gw] = a / (s + 1e-8f);
  }
}

// ---- kernel 2: fused dots + exact top-20 + softmax + full output write ----
__global__ __launch_bounds__(256) void k_main(
    const float* __restrict__ emb, const float* __restrict__ Ap,
    const float* __restrict__ aInv, const float* __restrict__ alpha,
    float* __restrict__ out) {
  __shared__ float se[CHUNK * EST];                      // 20480 B
  __shared__ unsigned long long cand[RPB][CCAP];         // 4096 B
  __shared__ int cur[RPB];

  const int tid = threadIdx.x;
  const int lane = tid & 63;
  const int wv = tid >> 6;              // wave 0..3
  const int b = blockIdx.x >> 8;        // 256 blocks per batch
  const int rg = blockIdx.x & 255;
  const int nbase = rg * RPB;

  for (int i = tid; i < RPB * CCAP; i += 256) ((unsigned long long*)cand)[i] = 0ull;
  if (tid < RPB) cur[tid] = 0;

  const float* embB = emb + (size_t)b * NN * NH;

  // this wave's 2 query embeddings (broadcast per lane)
  float en[RPW][NH];
#pragma unroll
  for (int r = 0; r < RPW; ++r) {
    const float* ep = embB + (size_t)(nbase + wv * RPW + r) * NH;
#pragma unroll
    for (int h = 0; h < NH; ++h) en[r][h] = ep[h];
  }

  float g[RPW][32];       // per-lane relu'd dot values, m = lane + 64*slot
  float lmax[RPW];
#pragma unroll
  for (int r = 0; r < RPW; ++r) lmax[r] = -1.0f;

  // ---- pass 1: stage emb chunks to LDS, compute all dots ----
#pragma unroll
  for (int c = 0; c < NCH; ++c) {
    __syncthreads();
    {
      const float4* src = (const float4*)(embB + (size_t)(c * CHUNK + tid) * NH);
      float4 v0 = src[0], v1 = src[1], v2 = src[2], v3 = src[3];
      float* dst = se + tid * EST;
      *(float4*)(dst + 0) = v0;
      *(float4*)(dst + 4) = v1;
      *(float4*)(dst + 8) = v2;
      *(float4*)(dst + 12) = v3;
    }
    __syncthreads();
#pragma unroll
    for (int j = 0; j < JST; ++j) {
      const float* em = se + (size_t)(j * 64 + lane) * EST;
      float4 e0 = *(const float4*)(em + 0);
      float4 e1 = *(const float4*)(em + 4);
      float4 e2 = *(const float4*)(em + 8);
      float4 e3 = *(const float4*)(em + 12);
#pragma unroll
      for (int r = 0; r < RPW; ++r) {
        float acc = 0.0f;
        acc = __fmaf_rn(en[r][0], e0.x, acc);
        acc = __fmaf_rn(en[r][1], e0.y, acc);
        acc = __fmaf_rn(en[r][2], e0.z, acc);
        acc = __fmaf_rn(en[r][3], e0.w, acc);
        acc = __fmaf_rn(en[r][4], e1.x, acc);
        acc = __fmaf_rn(en[r][5], e1.y, acc);
        acc = __fmaf_rn(en[r][6], e1.z, acc);
        acc = __fmaf_rn(en[r][7], e1.w, acc);
        acc = __fmaf_rn(en[r][8], e2.x, acc);
        acc = __fmaf_rn(en[r][9], e2.y, acc);
        acc = __fmaf_rn(en[r][10], e2.z, acc);
        acc = __fmaf_rn(en[r][11], e2.w, acc);
        acc = __fmaf_rn(en[r][12], e3.x, acc);
        acc = __fmaf_rn(en[r][13], e3.y, acc);
        acc = __fmaf_rn(en[r][14], e3.z, acc);
        acc = __fmaf_rn(en[r][15], e3.w, acc);
        acc = fmaxf(acc, 0.0f);          // relu before ranking (matches ref)
        g[r][c * JST + j] = acc;
        lmax[r] = fmaxf(lmax[r], acc);
      }
    }
  }
  // NOTE: no __syncthreads() below this point (waves diverge per-row).

  float av = 1.0f / (1.0f + expf(-alpha[0]));
  float oma = 1.0f - av;

  float wsel[RPW];
  unsigned msel[RPW];

#pragma unroll
  for (int r = 0; r < RPW; ++r) {
    const int rb = wv * RPW + r;
    // 1) bitonic-sort the 64 lane-maxes (desc); t_hat = 20th largest, a lower bound on v20
    float v = lmax[r];
#pragma unroll
    for (int k = 2; k <= 64; k <<= 1) {
#pragma unroll
      for (int m = k >> 1; m > 0; m >>= 1) {
        float o = __shfl_xor(v, m, 64);
        bool up = (lane & k) != 0;
        bool takeMax = ((lane & m) == 0) ^ up;
        v = takeMax ? fmaxf(v, o) : fminf(v, o);
      }
    }
    float th = __shfl(v, 19, 64);
    // 2) count candidates >= th
    int cnt = 0;
#pragma unroll
    for (int j = 0; j < 32; ++j) cnt += (g[r][j] >= th) ? 1 : 0;
#pragma unroll
    for (int off = 32; off; off >>= 1) cnt += __shfl_xor(cnt, off, 64);

    unsigned long long key;
    if (cnt <= CCAP) {
      // 3a) collect candidates, sort (val desc, idx asc) via packed u64 keys
#pragma unroll
      for (int j = 0; j < 32; ++j) {
        if (g[r][j] >= th) {
          int slot = atomicAdd(&cur[rb], 1);
          unsigned idx = (unsigned)(lane + 64 * j);
          cand[rb][slot] =
              ((unsigned long long)__float_as_uint(g[r][j]) << 32) | (unsigned)(~idx);
        }
      }
      asm volatile("s_waitcnt lgkmcnt(0)" ::: "memory");
      key = cand[rb][lane];
#pragma unroll
      for (int k = 2; k <= 64; k <<= 1) {
#pragma unroll
        for (int m = k >> 1; m > 0; m >>= 1) {
          unsigned long long o = shflxor64(key, m);
          bool up = (lane & k) != 0;
          bool takeMax = ((lane & m) == 0) ^ up;
          key = (takeMax == (key > o)) ? key : o;
        }
      }
    } else {
      // 3b) rare exact fallback (flat rows / ReLU-zero ties): 20x wave argmax
      unsigned taken = 0u;
      for (int sel = 0; sel < NK; ++sel) {
        float bv = -1.0f;
        int bj = 0;
#pragma unroll
        for (int j = 0; j < 32; ++j) {
          bool ok = ((taken >> j) & 1u) == 0u;
          bool bet = ok && (g[r][j] > bv);
          bv = bet ? g[r][j] : bv;
          bj = bet ? j : bj;
        }
        unsigned idx = (unsigned)(lane + 64 * bj);
        unsigned long long kk = ((unsigned long long)__float_as_uint(bv) << 32) | (unsigned)(~idx);
#pragma unroll
        for (int off = 32; off; off >>= 1) {
          unsigned long long o = shflxor64(kk, off);
          kk = (o > kk) ? o : kk;
        }
        unsigned wi = ~(unsigned)kk;
        if ((wi & 63u) == (unsigned)lane) taken |= (1u << (wi >> 6));
        if (lane == 0) cand[rb][sel] = kk;
      }
      asm volatile("s_waitcnt lgkmcnt(0)" ::: "memory");
      key = (lane < NK) ? cand[rb][lane] : 0ull;
    }

    // 4) softmax over the 20 selected (lanes 0..19 hold them desc-sorted)
    float vs = __uint_as_float((unsigned)(key >> 32));
    float vmax = __shfl(vs, 0, 64);
    float ex = (lane < NK) ? expf(vs - vmax) : 0.0f;
    float ssum = ex;
#pragma unroll
    for (int off = 32; off; off >>= 1) ssum += __shfl_xor(ssum, off, 64);
    wsel[r] = ex / ssum;
    msel[r] = ~(unsigned)key;
  }

  // ---- dense base write: a * A_phys_norm broadcast ----
#pragma unroll
  for (int r = 0; r < RPW; ++r) {
    int n = nbase + wv * RPW + r;
    float ai = aInv[n];
    const float4* pr = (const float4*)(Ap + (size_t)n * NN);
    float4* orow = (float4*)(out + ((size_t)b * NN + n) * NN);
#pragma unroll
    for (int f = 0; f < NN / 256; ++f) {
      int fi = lane + 64 * f;
      float4 p = pr[fi];
      float4 o;
      o.x = __fmul_rn(p.x, ai);
      o.y = __fmul_rn(p.y, ai);
      o.z = __fmul_rn(p.z, ai);
      o.w = __fmul_rn(p.w, ai);
      orow[fi] = o;
    }
  }
  // drain this wave's base stores before overwriting sparse positions
  asm volatile("s_waitcnt vmcnt(0)" ::: "memory");
#pragma unroll
  for (int r = 0; r < RPW; ++r) {
    if (lane < NK) {
      int n = nbase + wv * RPW + r;
      float ai = aInv[n];
      unsigned mi = msel[r];
      float p = Ap[(size_t)n * NN + mi];
      out[((size_t)b * NN + n) * NN + mi] =
          __fadd_rn(__fmul_rn(p, ai), __fmul_rn(oma, wsel[r]));
    }
  }
}

extern "C" void kernel_launch(void* const* d_in, const int* in_sizes, int n_in,
                              void* d_out, int out_size, void* d_ws, size_t ws_size,
                              hipStream_t stream) {
  const float* x = (const float*)d_in[0];
  const float* Ap = (const float*)d_in[1];
  const float* W = (const float*)d_in[2];
  const float* bb = (const float*)d_in[3];
  const float* alpha = (const float*)d_in[4];
  float* out = (float*)d_out;

  float* emb = (float*)d_ws;                        // 16*2048*16 f32 = 2 MB
  float* aInv = emb + (size_t)NB * NN * NH;         // 2048 f32

  hipLaunchKernelGGL(k_emb, dim3((NB * NN + 255) / 256), dim3(256), 0, stream,
                     x, W, bb, emb);
  hipLaunchKernelGGL(k_rowsum, dim3((NN * 64) / 256), dim3(256), 0, stream,
                     Ap, alpha, aInv);
  hipLaunchKernelGGL(k_main, dim3(NB * (NN / RPB)), dim3(256), 0, stream,
                     emb, Ap, aInv, alpha, out);
}